// Round 8
// baseline (532.844 us; speedup 1.0000x reference)
//
#include <hip/hip_runtime.h>
#include <cmath>

// Problem dims (fixed by setup_inputs)
#define B_SZ  32
#define LATD  64
#define HU    96
#define G4    384
#define T_LEN 512
#define VOC   10000
#define NROWS (B_SZ * T_LEN)        // 16384
#define NC16  625                   // 10000/16 exactly
#define NSPLIT 5
#define C16S  125                   // c16 tiles per split
#define RBLK  32                    // rows per dense block
#define PPR   (NSPLIT * 2)          // partials per row
#define HIST  64                    // LDS h-history ring depth
#define HALF  256                   // LSTM steps per kernel
#define PACK_BLOCKS 313             // ceil(625*3*64 / 384)
#define D0H_BLOCKS  (256 * NSPLIT)  // 1280: half the row-blocks x splits

typedef __attribute__((ext_vector_type(8))) short bf16x8;
typedef __attribute__((ext_vector_type(4))) float f32x4;

#define LOG2E  1.4426950408889634f
#define LOG2E2 2.8853900817779268f

__device__ __forceinline__ unsigned short f2bf(float x) {
  unsigned u = __float_as_uint(x);
  u += 0x7fffu + ((u >> 16) & 1u);   // RNE
  return (unsigned short)(u >> 16);
}
__device__ __forceinline__ float rcpf(float x) { return __builtin_amdgcn_rcpf(x); }
__device__ __forceinline__ float exp2f_(float x) { return __builtin_amdgcn_exp2f(x); }

// ---------------- LSTM body: 6 waves, gate-quad-in-lane, LDS h-ring ---------
// Replicated-A MFMA (A = h broadcast to 16 rows), B = U fragments pre-scaled
// by -log2e (i,f,o) / +2log2e (cbar) so activations use exp2 directly:
//   sig(g) = rcp(1+exp2(g'))        g' = -log2e*g
//   tanh(g) = 1-2*rcp(1+exp2(g2))   g2 = 2log2e*g
// Three independent MFMAs per gate (1x MFMA latency + add tree).
__device__ __forceinline__ void lstm_body(
    const float* __restrict__ z, const float* __restrict__ W,
    const float* __restrict__ U, const float* __restrict__ bias,
    unsigned short* __restrict__ hsb, float* __restrict__ c_save, int s0,
    unsigned short (*ring)[HU], float* z_lds) {
  const int tid = threadIdx.x;
  const int bb  = blockIdx.x;
  const int l   = tid & 63, wv = tid >> 6;   // wave 0..5
  const int c   = l & 15, kg = l >> 4, k0 = kg * 8;
  const int u0  = c + 16 * wv;
  unsigned short* hrow = hsb + (size_t)bb * T_LEN * HU;

  if (tid < LATD) z_lds[tid] = z[bb * LATD + tid];
  if (tid < 12) {
    uint4 h0 = make_uint4(0u, 0u, 0u, 0u);
    if (s0 != 0) h0 = ((const uint4*)(hrow + (size_t)(HALF - 1) * HU))[tid];
    ((uint4*)(ring[HIST - 1]))[tid] = h0;
  }

  // gate g of unit (c + 16*wv) lives at col (6g+wv)*16 + c
  int cols[4];
#pragma unroll
  for (int g = 0; g < 4; ++g) cols[g] = (6 * g + wv) * 16 + c;
  const float GS[4] = {-LOG2E, -LOG2E, LOG2E2, -LOG2E};

  // U fragments (MFMA B-operand layout), pre-scaled: 48 VGPRs
  bf16x8 Ufr[4][3];
#pragma unroll
  for (int g = 0; g < 4; ++g) {
#pragma unroll
    for (int kt = 0; kt < 3; ++kt) {
      const int kb = kt * 32 + k0;
      unsigned wb[4];
#pragma unroll
      for (int jj = 0; jj < 4; ++jj) {
        float x0 = U[(size_t)(kb + 2 * jj) * G4 + cols[g]] * GS[g];
        float x1 = U[(size_t)(kb + 2 * jj + 1) * G4 + cols[g]] * GS[g];
        wb[jj] = (unsigned)f2bf(x0) | ((unsigned)f2bf(x1) << 16);
      }
      uint4 u4 = make_uint4(wb[0], wb[1], wb[2], wb[3]);
      Ufr[g][kt] = __builtin_bit_cast(bf16x8, u4);
    }
  }

  float zp[4];
#pragma unroll
  for (int g = 0; g < 4; ++g) zp[g] = bias[cols[g]];
  __syncthreads();  // z_lds + ring init visible
  for (int k = 0; k < LATD; ++k) {
    const float zk = z_lds[k];
    const float* wr = W + (size_t)k * G4;
#pragma unroll
    for (int g = 0; g < 4; ++g) zp[g] = fmaf(zk, wr[cols[g]], zp[g]);
  }
#pragma unroll
  for (int g = 0; g < 4; ++g) zp[g] *= GS[g];

  float cst = (s0 == 0) ? 0.f : c_save[bb * HU + u0];
  const f32x4 zero4 = {0.f, 0.f, 0.f, 0.f};

  for (int ls = 0; ls < HALF; ++ls) {
    const int rs = (ls + HIST - 1) & (HIST - 1);
    bf16x8 afr[3];
#pragma unroll
    for (int kt = 0; kt < 3; ++kt)
      afr[kt] = *(const bf16x8*)(&ring[rs][kt * 32 + k0]);

    float g4v[4];
#pragma unroll
    for (int g = 0; g < 4; ++g) {
      f32x4 da = __builtin_amdgcn_mfma_f32_16x16x32_bf16(afr[0], Ufr[g][0], zero4, 0, 0, 0);
      f32x4 db = __builtin_amdgcn_mfma_f32_16x16x32_bf16(afr[1], Ufr[g][1], zero4, 0, 0, 0);
      f32x4 dc = __builtin_amdgcn_mfma_f32_16x16x32_bf16(afr[2], Ufr[g][2], zero4, 0, 0, 0);
      g4v[g] = (da[0] + db[0]) + (dc[0] + zp[g]);
    }

    const float i_ = rcpf(1.f + exp2f_(g4v[0]));
    const float f_ = rcpf(1.f + exp2f_(g4v[1]));
    const float cb = 1.f - 2.f * rcpf(1.f + exp2f_(g4v[2]));
    const float o_ = rcpf(1.f + exp2f_(g4v[3]));
    cst = f_ * cst + i_ * cb;
    const float th = 1.f - 2.f * rcpf(1.f + exp2f_(LOG2E2 * cst));
    const float h  = o_ * th;
    if (kg == 0) ring[ls & (HIST - 1)][u0] = f2bf(h);
    __syncthreads();

    if ((ls & (HIST - 1)) == (HIST - 1)) {
      // bulk dump 64 rows -> global, coalesced
      const uint4* srcp = (const uint4*)ring;
      uint4* dstp = (uint4*)(hrow + (size_t)(s0 + ls - (HIST - 1)) * HU);
      for (int i = tid; i < HIST * HU / 8; i += 384) dstp[i] = srcp[i];
      __syncthreads();  // ring reusable after dump reads done
    }
  }
  if (s0 == 0 && kg == 0) c_save[bb * HU + u0] = cst;
}

// ---------------- dense body (operand-swapped MFMA, 2-pass recompute) -------
// 4 waves: rt = wv&1 (16-row tile), cg = wv>>1 (odd/even c16 within split).
// acc = mfma(Wd_frag, hs_frag): lane (l15,l4) holds 4 consecutive cols
// (c16*16+l4*4+q) of row R0+rt*16+l15 -> float4 stores / float4 bd loads.
// PASS 0: partial sum(exp(logit)) -> part[row][s*2+cg].
// PASS 1: sums part inline -> invS; recomputes logits -> nontemporal out.
template <int PASS, int NT>
__device__ __forceinline__ void dense_body(
    const unsigned short* __restrict__ hsb, const bf16x8* __restrict__ Bp,
    const float* __restrict__ bd, const float* __restrict__ part,
    float* __restrict__ outp, unsigned short* Al, int R0, int s, int tid) {
  {
    const uint4* src = (const uint4*)(hsb + (size_t)R0 * HU);
    uint4* dst = (uint4*)Al;
    for (int i = tid; i < RBLK * HU / 8; i += NT) dst[i] = src[i];
  }
  __syncthreads();
  if (tid >= 256) return;  // K2 runs this body with 384-thread blocks

  const int l = tid & 63, wv = tid >> 6;
  const int rt = wv & 1, cg = wv >> 1;
  const int l15 = l & 15, l4 = l >> 4;

  bf16x8 afr[3];
#pragma unroll
  for (int kt = 0; kt < 3; ++kt)
    afr[kt] = *(const bf16x8*)(Al + (rt * 16 + l15) * HU + kt * 32 + l4 * 8);

  const int row = R0 + rt * 16 + l15;
  float iv = 0.f;
  if (PASS == 1) {
    float sum = 0.f;
#pragma unroll
    for (int i = 0; i < PPR; ++i) sum += part[(size_t)row * PPR + i];
    iv = 1.f / sum;
  }

  float srun = 0.f;
  for (int i = cg; i < C16S; i += 2) {
    const int c16 = s * C16S + i;
    const bf16x8* bp = Bp + (size_t)c16 * 192 + l;
    const bf16x8 b0 = bp[0], b1 = bp[64], b2 = bp[128];
    f32x4 acc = {0.f, 0.f, 0.f, 0.f};
    acc = __builtin_amdgcn_mfma_f32_16x16x32_bf16(b0, afr[0], acc, 0, 0, 0);
    acc = __builtin_amdgcn_mfma_f32_16x16x32_bf16(b1, afr[1], acc, 0, 0, 0);
    acc = __builtin_amdgcn_mfma_f32_16x16x32_bf16(b2, afr[2], acc, 0, 0, 0);
    const int colb = c16 * 16 + l4 * 4;
    const f32x4 bd4 = *(const f32x4*)(bd + colb);
    if (PASS == 0) {
#pragma unroll
      for (int q = 0; q < 4; ++q) srun += __expf(acc[q] + bd4[q]);
    } else {
      f32x4 o;
#pragma unroll
      for (int q = 0; q < 4; ++q) o[q] = __expf(acc[q] + bd4[q]) * iv;
      __builtin_nontemporal_store(o, (f32x4*)(outp + (size_t)row * VOC + colb));
    }
  }

  if (PASS == 0) {
    srun += __shfl_xor(srun, 16);
    srun += __shfl_xor(srun, 32);
    if (l4 == 0)
      ((float*)outp)[(size_t)row * PPR + s * 2 + cg] = srun;  // outp = part
  }
}

// Half-row-block mapping: row r = bb*512 + t; half 0 = t<256 <=> (rb&15)<8.
__device__ __forceinline__ int rb_of_half(int j, int hi) {
  return (j >> 3) * 16 + hi * 8 + (j & 7);
}

// ---------------- K1: LSTM steps 0..255 + Wd packing ------------------------
__global__ __launch_bounds__(384) void k1_lstm_pack(
    const float* __restrict__ z, const float* __restrict__ W,
    const float* __restrict__ U, const float* __restrict__ bias,
    const float* __restrict__ Wd, unsigned short* __restrict__ hsb,
    uint4* __restrict__ Bp, float* __restrict__ c_save) {
  if (blockIdx.x >= B_SZ) {
    const int gid = (blockIdx.x - B_SZ) * 384 + threadIdx.x;
    if (gid < NC16 * 3 * 64) {
      const int l   = gid & 63;
      const int K16 = (gid >> 6) % 3;
      const int c16 = gid / 192;
      const int col = c16 * 16 + (l & 15);
      const int k0  = K16 * 32 + (l >> 4) * 8;
      unsigned wb[4];
#pragma unroll
      for (int jj = 0; jj < 4; ++jj) {
        float x0 = Wd[(size_t)(k0 + 2 * jj) * VOC + col];
        float x1 = Wd[(size_t)(k0 + 2 * jj + 1) * VOC + col];
        wb[jj] = (unsigned)f2bf(x0) | ((unsigned)f2bf(x1) << 16);
      }
      Bp[gid] = make_uint4(wb[0], wb[1], wb[2], wb[3]);
    }
    return;
  }
  __shared__ __align__(16) unsigned short ring[HIST][HU];
  __shared__ float z_lds[LATD];
  lstm_body(z, W, U, bias, hsb, c_save, 0, ring, z_lds);
}

// ---------------- K2: LSTM steps 256..511 + dense pass0 (t<256 rows) --------
__global__ __launch_bounds__(384) void k2_lstm_d0(
    const float* __restrict__ z, const float* __restrict__ W,
    const float* __restrict__ U, const float* __restrict__ bias,
    unsigned short* __restrict__ hsb, const bf16x8* __restrict__ Bp,
    const float* __restrict__ bd, float* __restrict__ part,
    float* __restrict__ c_save) {
  if (blockIdx.x >= B_SZ) {
    __shared__ __align__(16) unsigned short Al[RBLK * HU];
    const int db = blockIdx.x - B_SZ;
    const int s = db / 256, j = db % 256;
    dense_body<0, 384>(hsb, Bp, bd, nullptr, part, Al,
                       rb_of_half(j, 0) * RBLK, s, threadIdx.x);
    return;
  }
  __shared__ __align__(16) unsigned short ring[HIST][HU];
  __shared__ float z_lds[LATD];
  lstm_body(z, W, U, bias, hsb, c_save, HALF, ring, z_lds);
}

// ---------------- K3: dense pass0 (t>=256) + dense pass1 (t<256) ------------
__global__ __launch_bounds__(256) void k3_d0_d1(
    const unsigned short* __restrict__ hsb, const bf16x8* __restrict__ Bp,
    const float* __restrict__ bd, float* __restrict__ part,
    float* __restrict__ out) {
  __shared__ __align__(16) unsigned short Al[RBLK * HU];
  if (blockIdx.x < D0H_BLOCKS) {
    const int s = blockIdx.x / 256, j = blockIdx.x % 256;
    dense_body<0, 256>(hsb, Bp, bd, nullptr, part, Al,
                       rb_of_half(j, 1) * RBLK, s, threadIdx.x);
  } else {
    const int db = blockIdx.x - D0H_BLOCKS;
    const int s = db / 256, j = db % 256;
    dense_body<1, 256>(hsb, Bp, bd, part, out, Al,
                       rb_of_half(j, 0) * RBLK, s, threadIdx.x);
  }
}

// ---------------- K4: dense pass1 (t>=256) ----------------------------------
__global__ __launch_bounds__(256) void k4_d1(
    const unsigned short* __restrict__ hsb, const bf16x8* __restrict__ Bp,
    const float* __restrict__ bd, const float* __restrict__ part,
    float* __restrict__ out) {
  __shared__ __align__(16) unsigned short Al[RBLK * HU];
  const int s = blockIdx.x / 256, j = blockIdx.x % 256;
  dense_body<1, 256>(hsb, Bp, bd, part, out, Al,
                     rb_of_half(j, 1) * RBLK, s, threadIdx.x);
}

extern "C" void kernel_launch(void* const* d_in, const int* in_sizes, int n_in,
                              void* d_out, int out_size, void* d_ws, size_t ws_size,
                              hipStream_t stream) {
  const float* z  = (const float*)d_in[0];
  const float* W  = (const float*)d_in[1];
  const float* U  = (const float*)d_in[2];
  const float* b  = (const float*)d_in[3];
  const float* Wd = (const float*)d_in[4];
  const float* bd = (const float*)d_in[5];
  float* out = (float*)d_out;

  char* ws = (char*)d_ws;
  unsigned short* hsb = (unsigned short*)ws;                 // 3,145,728 B
  uint4* Bp    = (uint4*)(ws + 3145728);                     // 1,920,000 B
  float* part  = (float*)(ws + 3145728 + 1920000);           //   655,360 B
  float* c_save = (float*)(ws + 3145728 + 1920000 + 655360); //    12,288 B

  k1_lstm_pack<<<B_SZ + PACK_BLOCKS, 384, 0, stream>>>(z, W, U, b, Wd, hsb, Bp, c_save);
  k2_lstm_d0<<<B_SZ + D0H_BLOCKS, 384, 0, stream>>>(z, W, U, b, hsb,
                                                    (const bf16x8*)Bp, bd, part, c_save);
  k3_d0_d1<<<2 * D0H_BLOCKS, 256, 0, stream>>>(hsb, (const bf16x8*)Bp, bd, part, out);
  k4_d1<<<D0H_BLOCKS, 256, 0, stream>>>(hsb, (const bf16x8*)Bp, bd, part, out);
}